// Round 11
// baseline (263.303 us; speedup 1.0000x reference)
//
#include <hip/hip_runtime.h>
#include <hip/hip_bf16.h>
#include <stdint.h>

// 2-layer GCN, N=100000, E=3200000, F=128, H=64.
// out = b2 + (1/N)*sum_i dinv[i]*( yp[i] + sum_{j in Nin(i)} yp[j] )
// yp[i] = dinv[i]*relu(b1 + dinv[i]*(sum_{e:col=i} xws[row] + xws[i])).W2
// xws[j] = dinv[j]*(x@W1)[j] stored FP8 e4m3, SPLIT into two 3.2MB feature
// halves; aggregation runs twice so each pass's gather table FITS per-XCD L2
// (4MB). r10 showed k_agg is miss-latency bound (66us at 99MB or 157MB
// FETCH alike); the only lever is making misses vanish via L2 residency.
// HW lessons baked in:
//  - global atomics are memory-side (~32B RMW each): zero on edge path.
//  - SAME-ADDRESS global atomics serialize ~12ns: per-block partials instead.
//  - aggregation needs ~100K waves (wave-per-node).

#define F_IN 128
#define H_DIM 64
#define BKT_SH 7
#define BKT_SZ 128
#define MAXBKT 1024
#define PWG 256
#define PTHR 256
#define FINBLK 2048

typedef int   i4 __attribute__((ext_vector_type(4)));
typedef float f4 __attribute__((ext_vector_type(4)));
typedef float fv2 __attribute__((ext_vector_type(2)));

#if defined(__has_builtin)
#if __has_builtin(__builtin_amdgcn_cvt_pk_f32_fp8) && __has_builtin(__builtin_amdgcn_cvt_pk_fp8_f32)
#define HW_FP8 1
#endif
#endif

__device__ __forceinline__ float sw_dec_e4m3(unsigned b) {
    unsigned s = b & 0x80, e = (b >> 3) & 15, mm = b & 7;
    float v;
    if (e) v = __uint_as_float(((e + 120u) << 23) | (mm << 20));
    else   v = (float)mm * 0.001953125f;
    return s ? -v : v;
}
__device__ __forceinline__ unsigned sw_enc_e4m3(float f) {
    unsigned s = (__float_as_uint(f) & 0x80000000u) ? 0x80u : 0u;
    float a = fminf(fabsf(f), 448.0f);
    if (a < 9.765625e-4f) return s;
    if (a < 0.015625f) {
        int k = (int)rintf(a * 512.0f);
        if (k > 7) return s | 0x08;
        return s | (unsigned)k;
    }
    int e; float mant = frexpf(a, &e);
    int q = (int)rintf((mant * 2.0f - 1.0f) * 8.0f);
    int E = e - 1;
    if (q == 8) { q = 0; E += 1; }
    if (E > 8) { E = 8; q = 6; }
    return s | ((unsigned)(E + 7) << 3) | (unsigned)q;
}

__device__ __forceinline__ float2 f8pair(unsigned u) {   // 2 fp8 in low 16 bits
#ifdef HW_FP8
    fv2 r = __builtin_amdgcn_cvt_pk_f32_fp8((int)u, false);
    return make_float2(r.x, r.y);
#else
    return make_float2(sw_dec_e4m3(u & 0xff), sw_dec_e4m3((u >> 8) & 0xff));
#endif
}
__device__ __forceinline__ unsigned f8pack4(float v0, float v1, float v2, float v3) {
#ifdef HW_FP8
    unsigned pk = (unsigned)__builtin_amdgcn_cvt_pk_fp8_f32(v0, v1, 0, false);
    pk = (unsigned)__builtin_amdgcn_cvt_pk_fp8_f32(v2, v3, (int)pk, true);
    return pk;
#else
    return sw_enc_e4m3(v0) | (sw_enc_e4m3(v1) << 8) |
           (sw_enc_e4m3(v2) << 16) | (sw_enc_e4m3(v3) << 24);
#endif
}

// ---------- pass 1: per-WG bucket histogram (LDS), int4 x4 streaming ----------
__global__ __launch_bounds__(PTHR) void k_hist1(const int* __restrict__ col,
                                                int* __restrict__ histG,
                                                int E, int nbkt, int chunk) {
    __shared__ int h[MAXBKT];
    for (int i = threadIdx.x; i < nbkt; i += PTHR) h[i] = 0;
    __syncthreads();
    int s = blockIdx.x * chunk, e = min(E, s + chunk);
    if (s < e) {
        int s4 = s >> 2, e4 = e >> 2;
        const i4* c4 = (const i4*)col;
        int t = s4 + threadIdx.x;
        for (; t + 3 * PTHR < e4; t += 4 * PTHR) {
            i4 a = __builtin_nontemporal_load(c4 + t);
            i4 b = __builtin_nontemporal_load(c4 + t + PTHR);
            i4 c = __builtin_nontemporal_load(c4 + t + 2 * PTHR);
            i4 d = __builtin_nontemporal_load(c4 + t + 3 * PTHR);
            atomicAdd(&h[a.x >> BKT_SH], 1); atomicAdd(&h[a.y >> BKT_SH], 1);
            atomicAdd(&h[a.z >> BKT_SH], 1); atomicAdd(&h[a.w >> BKT_SH], 1);
            atomicAdd(&h[b.x >> BKT_SH], 1); atomicAdd(&h[b.y >> BKT_SH], 1);
            atomicAdd(&h[b.z >> BKT_SH], 1); atomicAdd(&h[b.w >> BKT_SH], 1);
            atomicAdd(&h[c.x >> BKT_SH], 1); atomicAdd(&h[c.y >> BKT_SH], 1);
            atomicAdd(&h[c.z >> BKT_SH], 1); atomicAdd(&h[c.w >> BKT_SH], 1);
            atomicAdd(&h[d.x >> BKT_SH], 1); atomicAdd(&h[d.y >> BKT_SH], 1);
            atomicAdd(&h[d.z >> BKT_SH], 1); atomicAdd(&h[d.w >> BKT_SH], 1);
        }
        for (; t < e4; t += PTHR) {
            i4 a = __builtin_nontemporal_load(c4 + t);
            atomicAdd(&h[a.x >> BKT_SH], 1); atomicAdd(&h[a.y >> BKT_SH], 1);
            atomicAdd(&h[a.z >> BKT_SH], 1); atomicAdd(&h[a.w >> BKT_SH], 1);
        }
        for (int i = (e4 << 2) + threadIdx.x; i < e; i += PTHR)
            atomicAdd(&h[col[i] >> BKT_SH], 1);
    }
    __syncthreads();
    for (int i = threadIdx.x; i < nbkt; i += PTHR)
        histG[(size_t)i * PWG + blockIdx.x] = h[i];
}

// ---------- pass 2a: per-bucket exclusive scan over WGs (in place) ----------
__global__ __launch_bounds__(PWG) void k_hscan_a(int* __restrict__ histG,
                                                 int* __restrict__ total, int nbkt) {
    __shared__ int s[PWG];
    int b = blockIdx.x, t = threadIdx.x;
    int v = histG[(size_t)b * PWG + t];
    s[t] = v;
    __syncthreads();
    for (int d = 1; d < PWG; d <<= 1) {
        int a = (t >= d) ? s[t - d] : 0;
        __syncthreads();
        s[t] += a;
        __syncthreads();
    }
    histG[(size_t)b * PWG + t] = s[t] - v;
    if (t == PWG - 1) total[b] = s[t];
}

// ---------- pass 2b: bucket starts ----------
__global__ __launch_bounds__(1024) void k_hscan_b(const int* __restrict__ total,
                                                  int* __restrict__ bstart, int nbkt) {
    __shared__ int s[1024];
    int t = threadIdx.x;
    int v = (t < nbkt) ? total[t] : 0;
    s[t] = v;
    __syncthreads();
    for (int d = 1; d < 1024; d <<= 1) {
        int a = (t >= d) ? s[t - d] : 0;
        __syncthreads();
        s[t] += a;
        __syncthreads();
    }
    if (t < nbkt) bstart[t] = s[t] - v;
    if (t == nbkt - 1) bstart[nbkt] = s[t];
}

// ---------- pass 3: partition edges, packed (row<<7)|colLocal ----------
__global__ __launch_bounds__(PTHR) void k_part(const int* __restrict__ row,
                                               const int* __restrict__ col,
                                               const int* __restrict__ histG,
                                               const int* __restrict__ bstart,
                                               unsigned int* __restrict__ part,
                                               int E, int nbkt, int chunk) {
    __shared__ int cur[MAXBKT];
    for (int i = threadIdx.x; i < nbkt; i += PTHR)
        cur[i] = bstart[i] + histG[(size_t)i * PWG + blockIdx.x];
    __syncthreads();
    int s = blockIdx.x * chunk, e = min(E, s + chunk);
    if (s >= e) return;
    int s4 = s >> 2, e4 = e >> 2;
    const i4* c4 = (const i4*)col;
    const i4* r4 = (const i4*)row;
    int t = s4 + threadIdx.x;
    for (; t + PTHR < e4; t += 2 * PTHR) {
        i4 ca = __builtin_nontemporal_load(c4 + t);
        i4 ra = __builtin_nontemporal_load(r4 + t);
        i4 cb = __builtin_nontemporal_load(c4 + t + PTHR);
        i4 rb = __builtin_nontemporal_load(r4 + t + PTHR);
        int p;
        p = atomicAdd(&cur[ca.x >> BKT_SH], 1);
        part[p] = ((unsigned int)ra.x << BKT_SH) | (unsigned int)(ca.x & (BKT_SZ - 1));
        p = atomicAdd(&cur[ca.y >> BKT_SH], 1);
        part[p] = ((unsigned int)ra.y << BKT_SH) | (unsigned int)(ca.y & (BKT_SZ - 1));
        p = atomicAdd(&cur[ca.z >> BKT_SH], 1);
        part[p] = ((unsigned int)ra.z << BKT_SH) | (unsigned int)(ca.z & (BKT_SZ - 1));
        p = atomicAdd(&cur[ca.w >> BKT_SH], 1);
        part[p] = ((unsigned int)ra.w << BKT_SH) | (unsigned int)(ca.w & (BKT_SZ - 1));
        p = atomicAdd(&cur[cb.x >> BKT_SH], 1);
        part[p] = ((unsigned int)rb.x << BKT_SH) | (unsigned int)(cb.x & (BKT_SZ - 1));
        p = atomicAdd(&cur[cb.y >> BKT_SH], 1);
        part[p] = ((unsigned int)rb.y << BKT_SH) | (unsigned int)(cb.y & (BKT_SZ - 1));
        p = atomicAdd(&cur[cb.z >> BKT_SH], 1);
        part[p] = ((unsigned int)rb.z << BKT_SH) | (unsigned int)(cb.z & (BKT_SZ - 1));
        p = atomicAdd(&cur[cb.w >> BKT_SH], 1);
        part[p] = ((unsigned int)rb.w << BKT_SH) | (unsigned int)(cb.w & (BKT_SZ - 1));
    }
    for (; t < e4; t += PTHR) {
        i4 ca = __builtin_nontemporal_load(c4 + t);
        i4 ra = __builtin_nontemporal_load(r4 + t);
        int p;
        p = atomicAdd(&cur[ca.x >> BKT_SH], 1);
        part[p] = ((unsigned int)ra.x << BKT_SH) | (unsigned int)(ca.x & (BKT_SZ - 1));
        p = atomicAdd(&cur[ca.y >> BKT_SH], 1);
        part[p] = ((unsigned int)ra.y << BKT_SH) | (unsigned int)(ca.y & (BKT_SZ - 1));
        p = atomicAdd(&cur[ca.z >> BKT_SH], 1);
        part[p] = ((unsigned int)ra.z << BKT_SH) | (unsigned int)(ca.z & (BKT_SZ - 1));
        p = atomicAdd(&cur[ca.w >> BKT_SH], 1);
        part[p] = ((unsigned int)ra.w << BKT_SH) | (unsigned int)(ca.w & (BKT_SZ - 1));
    }
    for (int i = (e4 << 2) + threadIdx.x; i < e; i += PTHR) {
        int c = col[i], r = row[i];
        int p = atomicAdd(&cur[c >> BKT_SH], 1);
        part[p] = ((unsigned int)r << BKT_SH) | (unsigned int)(c & (BKT_SZ - 1));
    }
}

// ---------- per-bucket: degrees, offs, dinv, and CSR scatter ----------
__global__ __launch_bounds__(PTHR) void k_csr(const unsigned int* __restrict__ part,
                                              const int* __restrict__ bstart,
                                              int* __restrict__ offs,
                                              float* __restrict__ dinv,
                                              int* __restrict__ csr,
                                              int N, int E, int nbkt) {
    __shared__ int dg[BKT_SZ];
    __shared__ int sc[BKT_SZ];
    __shared__ int cur[BKT_SZ];
    int b = blockIdx.x, tid = threadIdx.x;
    if (tid < BKT_SZ) dg[tid] = 0;
    __syncthreads();
    int s = bstart[b], e = bstart[b + 1];
    for (int i = s + tid; i < e; i += PTHR)
        atomicAdd(&dg[part[i] & (BKT_SZ - 1)], 1);
    __syncthreads();
    if (tid < BKT_SZ) sc[tid] = dg[tid];
    __syncthreads();
    for (int d = 1; d < BKT_SZ; d <<= 1) {
        int v = (tid < BKT_SZ && tid >= d) ? sc[tid - d] : 0;
        __syncthreads();
        if (tid < BKT_SZ) sc[tid] += v;
        __syncthreads();
    }
    if (tid < BKT_SZ) {
        int ex = sc[tid] - dg[tid];
        cur[tid] = ex;
        int g = b * BKT_SZ + tid;
        if (g < N) {
            offs[g] = s + ex;
            dinv[g] = rsqrtf((float)dg[tid] + 1.0f);  // +1 self loop
        }
    }
    if (b == 0 && tid == 0) offs[N] = E;
    __syncthreads();
    for (int i = s + tid; i < e; i += PTHR) {
        unsigned int u = part[i];
        int cl = u & (BKT_SZ - 1);
        int p = atomicAdd(&cur[cl], 1);
        csr[s + p] = u >> BKT_SH;
    }
}

// ---------- xws = dinv * (x @ W1), fp8 e4m3, two 32-feat halves ----------
__global__ __launch_bounds__(256) void k_gemm1(const float* __restrict__ x,
                                               const float* __restrict__ W1,
                                               const float* __restrict__ dinv,
                                               unsigned int* __restrict__ xh0,
                                               unsigned int* __restrict__ xh1,
                                               int N) {
    __shared__ float xs[64 * 132];
    __shared__ float ws[128 * 64];
    int tid = threadIdx.x;
    int row0 = blockIdx.x * 64;

    const float4* w4 = (const float4*)W1;
    float4* ws4 = (float4*)ws;
#pragma unroll
    for (int i = 0; i < 8; i++) ws4[tid + 256 * i] = w4[tid + 256 * i];

#pragma unroll
    for (int i = 0; i < 8; i++) {
        int idx = tid + 256 * i;
        int r = idx >> 5;
        int c = idx & 31;
        f4 v = {0.f, 0.f, 0.f, 0.f};
        int gr = row0 + r;
        if (gr < N) v = __builtin_nontemporal_load((const f4*)x + (size_t)gr * 32 + c);
        *(f4*)&xs[r * 132 + c * 4] = v;
    }
    __syncthreads();

    int tx = tid & 15, ty = tid >> 4;
    float acc[4][4] = {};
#pragma unroll 4
    for (int k = 0; k < 128; k++) {
        float4 wv = *(const float4*)&ws[k * 64 + tx * 4];
#pragma unroll
        for (int i = 0; i < 4; i++) {
            float xv = xs[(ty * 4 + i) * 132 + k];
            acc[i][0] += xv * wv.x;
            acc[i][1] += xv * wv.y;
            acc[i][2] += xv * wv.z;
            acc[i][3] += xv * wv.w;
        }
    }
    unsigned int* dst = (tx < 8) ? xh0 : xh1;
    int txl = tx & 7;                // uint slot within 8-uint (32-fp8) row
#pragma unroll
    for (int i = 0; i < 4; i++) {
        int gr = row0 + ty * 4 + i;
        if (gr < N) {
            float dsc = dinv[gr];
            unsigned pk = f8pack4(acc[i][0] * dsc, acc[i][1] * dsc,
                                  acc[i][2] * dsc, acc[i][3] * dsc);
            dst[(size_t)gr * 8 + txl] = pk;
        }
    }
}

// ---------- aggregation pass P: quarter-wave ushort fp8 gathers on 32B rows ----------
// lane=(g,m): m=lane&15 feature-pair (2m,2m+1 of this 32-feat half),
// g=lane>>4 edge slot (4 edges per gather instr). 32-edge unroll = 8 in flight.
template<int P>
__global__ __launch_bounds__(256) void k_agg(const ushort* __restrict__ xh,
                                             const int* __restrict__ csr,
                                             const int* __restrict__ offs,
                                             const float* __restrict__ dinv,
                                             const float* __restrict__ b1,
                                             const float* __restrict__ W2,
                                             float* __restrict__ tmpv,
                                             float* __restrict__ yp, int N) {
    int wid = (blockIdx.x * blockDim.x + threadIdx.x) >> 6;
    int lane = threadIdx.x & 63;
    if (wid >= N) return;
    int m = lane & 15, g = lane >> 4;

    float di = dinv[wid];
    float a0 = 0.f, a1 = 0.f;
    if (g == 0) {          // self loop counted once
        float2 sv = f8pair(xh[(size_t)wid * 16 + m]);
        a0 += sv.x; a1 += sv.y;
    }
    int p = offs[wid], pe = offs[wid + 1];
    for (; p + 32 <= pe; p += 32) {
        int j[8]; ushort u[8];
#pragma unroll
        for (int q = 0; q < 8; q++) j[q] = csr[p + 4 * q + g];
#pragma unroll
        for (int q = 0; q < 8; q++) u[q] = xh[(size_t)j[q] * 16 + m];
#pragma unroll
        for (int q = 0; q < 8; q++) {
            float2 v = f8pair(u[q]);
            a0 += v.x; a1 += v.y;
        }
    }
    for (; p + 4 <= pe; p += 4) {
        int j = csr[p + g];
        float2 v = f8pair(xh[(size_t)j * 16 + m]);
        a0 += v.x; a1 += v.y;
    }
    int rem = pe - p;
    if (g < rem) {
        int j = csr[p + g];
        float2 v = f8pair(xh[(size_t)j * 16 + m]);
        a0 += v.x; a1 += v.y;
    }
    // reduce over the 4 edge slots (lane bits 4,5)
    a0 += __shfl_xor(a0, 16, 64); a0 += __shfl_xor(a0, 32, 64);
    a1 += __shfl_xor(a1, 16, 64); a1 += __shfl_xor(a1, 32, 64);
    float2 bv = ((const float2*)b1)[P * 16 + m];
    float2 wv = ((const float2*)W2)[P * 16 + m];
    float h0 = fmaxf(bv.x + di * a0, 0.f);
    float h1 = fmaxf(bv.y + di * a1, 0.f);
    float v = h0 * wv.x + h1 * wv.y;
    v += __shfl_xor(v, 1, 64);
    v += __shfl_xor(v, 2, 64);
    v += __shfl_xor(v, 4, 64);
    v += __shfl_xor(v, 8, 64);
    if (lane == 0) {
        if (P == 0) tmpv[wid] = v;
        else        yp[wid] = di * (tmpv[wid] + v);
    }
}

// ---------- final: wave-per-node over CSR, per-block partials ----------
__global__ __launch_bounds__(256) void k_final2(const int* __restrict__ csr,
                                                const int* __restrict__ offs,
                                                const float* __restrict__ dinv,
                                                const float* __restrict__ yp,
                                                float* __restrict__ partial, int N) {
    int lane = threadIdx.x & 63, w = threadIdx.x >> 6;
    int nwave_tot = gridDim.x * 4;
    int wid0 = blockIdx.x * 4 + w;
    float wpart = 0.f;
    for (int i = wid0; i < N; i += nwave_tot) {
        int p0 = offs[i], p1 = offs[i + 1];
        float s = (lane == 0) ? yp[i] : 0.f;
        for (int p = p0 + lane; p < p1; p += 64)
            s += yp[csr[p]];
#pragma unroll
        for (int d = 32; d > 0; d >>= 1) s += __shfl_xor(s, d, 64);
        if (lane == 0) wpart += dinv[i] * s;
    }
    __shared__ float wsum[4];
    if (lane == 0) wsum[w] = wpart;
    __syncthreads();
    if (threadIdx.x == 0)
        partial[blockIdx.x] = (wsum[0] + wsum[1]) + (wsum[2] + wsum[3]);
}

// ---------- reduce partials + write ----------
__global__ __launch_bounds__(256) void k_write(const float* __restrict__ partial,
                                               const float* __restrict__ b2,
                                               float* __restrict__ out, int nb, int N) {
    float s = 0.f;
    for (int i = threadIdx.x; i < nb; i += 256) s += partial[i];
#pragma unroll
    for (int d = 32; d > 0; d >>= 1) s += __shfl_xor(s, d, 64);
    __shared__ float wsum[4];
    int lane = threadIdx.x & 63, w = threadIdx.x >> 6;
    if (lane == 0) wsum[w] = s;
    __syncthreads();
    if (threadIdx.x == 0)
        out[0] = b2[0] + ((wsum[0] + wsum[1]) + (wsum[2] + wsum[3])) / (float)N;
}

extern "C" void kernel_launch(void* const* d_in, const int* in_sizes, int n_in,
                              void* d_out, int out_size, void* d_ws, size_t ws_size,
                              hipStream_t stream) {
    const float* x  = (const float*)d_in[0];
    const int*   ei = (const int*)d_in[1];
    const float* W1 = (const float*)d_in[2];
    const float* b1 = (const float*)d_in[3];
    const float* W2 = (const float*)d_in[4];
    const float* b2 = (const float*)d_in[5];

    int N = in_sizes[0] / F_IN;
    int E = in_sizes[1] / 2;
    const int* erow = ei;        // sources
    const int* ecol = ei + E;    // targets

    int NBKT = (N + BKT_SZ - 1) >> BKT_SH;
    int chunk = (((E + PWG - 1) / PWG) + 3) & ~3;   // 4-aligned chunks

    char* w = (char*)d_ws;
    auto take = [&](size_t bytes) {
        char* p = w;
        w += (bytes + 255) & ~(size_t)255;
        return p;
    };
    int*          histG   = (int*)take((size_t)NBKT * PWG * 4);
    int*          total   = (int*)take((size_t)NBKT * 4);
    int*          bstart  = (int*)take((size_t)(NBKT + 1) * 4);
    unsigned int* part    = (unsigned int*)take((size_t)E * 4);
    int*          csr     = (int*)take((size_t)E * 4);
    int*          offs    = (int*)take((size_t)(N + 1) * 4);
    float*        dinv    = (float*)take((size_t)N * 4);
    float*        yp      = (float*)take((size_t)N * 4);
    float*        tmpv    = (float*)take((size_t)N * 4);
    float*        partial = (float*)take((size_t)FINBLK * 4);
    unsigned int* xh0     = (unsigned int*)take((size_t)N * 32);
    unsigned int* xh1     = (unsigned int*)take((size_t)N * 32);
    (void)ws_size;

    float* out = (float*)d_out;

    k_hist1<<<PWG, PTHR, 0, stream>>>(ecol, histG, E, NBKT, chunk);
    k_hscan_a<<<NBKT, PWG, 0, stream>>>(histG, total, NBKT);
    k_hscan_b<<<1, 1024, 0, stream>>>(total, bstart, NBKT);
    k_part<<<PWG, PTHR, 0, stream>>>(erow, ecol, histG, bstart, part, E, NBKT, chunk);
    k_csr<<<NBKT, PTHR, 0, stream>>>(part, bstart, offs, dinv, csr, N, E, NBKT);
    k_gemm1<<<(N + 63) / 64, 256, 0, stream>>>(x, W1, dinv, xh0, xh1, N);
    int aggGrid = ((size_t)N * 64 + 255) / 256;
    k_agg<0><<<aggGrid, 256, 0, stream>>>((const ushort*)xh0, csr, offs, dinv, b1, W2, tmpv, yp, N);
    k_agg<1><<<aggGrid, 256, 0, stream>>>((const ushort*)xh1, csr, offs, dinv, b1, W2, tmpv, yp, N);
    k_final2<<<FINBLK, 256, 0, stream>>>(csr, offs, dinv, yp, partial, N);
    k_write<<<1, 256, 0, stream>>>(partial, b2, out, FINBLK, N);
}

// Round 12
// 195.634 us; speedup vs baseline: 1.3459x; 1.3459x over previous
//
#include <hip/hip_runtime.h>
#include <hip/hip_bf16.h>
#include <stdint.h>

// 2-layer GCN, N=100000, E=3200000, F=128, H=64.
// out = b2 + (1/N)*sum_i dinv[i]*( yp[i] + sum_{j in Nin(i)} yp[j] )
// yp[i] = dinv[i]*relu(b1 + dinv[i]*(sum_{e:col=i} xws[row] + xws[i])).W2
// xws[j] = dinv[j]*(x@W1)[j] stored FP8 e4m3, 64B rows (single table).
// HW model (measured r1-r11):
//  - global atomics are memory-side ~32B RMW each: zero on edge path.
//  - SAME-ADDRESS global atomics serialize ~12ns: per-block partials.
//  - random gathers/scatters cost ~8cyc per unique cache line per CU;
//    k_agg floor ~= 1.5 line-accesses/edge ~= 64us/pass -> SINGLE pass only
//    (r11's two L2-resident passes: misses vanished, time didn't).
//  - scattered 4B global writes (64 lines/instr) are the same cost class:
//    k_part/k_csr now group tiles in LDS and write coalesced runs.

#define F_IN 128
#define H_DIM 64
#define BKT_SH 8
#define BKT_SZ 256
#define MAXBKT 512
#define PWG 256
#define PTHR 256
#define PPTHR 512
#define TILE 4096
#define CSR_CAP 10240
#define FINBLK 2048

typedef int   i4 __attribute__((ext_vector_type(4)));
typedef float f4 __attribute__((ext_vector_type(4)));
typedef float fv2 __attribute__((ext_vector_type(2)));

#if defined(__has_builtin)
#if __has_builtin(__builtin_amdgcn_cvt_pk_f32_fp8) && __has_builtin(__builtin_amdgcn_cvt_pk_fp8_f32)
#define HW_FP8 1
#endif
#endif

__device__ __forceinline__ float sw_dec_e4m3(unsigned b) {
    unsigned s = b & 0x80, e = (b >> 3) & 15, mm = b & 7;
    float v;
    if (e) v = __uint_as_float(((e + 120u) << 23) | (mm << 20));
    else   v = (float)mm * 0.001953125f;
    return s ? -v : v;
}
__device__ __forceinline__ unsigned sw_enc_e4m3(float f) {
    unsigned s = (__float_as_uint(f) & 0x80000000u) ? 0x80u : 0u;
    float a = fminf(fabsf(f), 448.0f);
    if (a < 9.765625e-4f) return s;
    if (a < 0.015625f) {
        int k = (int)rintf(a * 512.0f);
        if (k > 7) return s | 0x08;
        return s | (unsigned)k;
    }
    int e; float mant = frexpf(a, &e);
    int q = (int)rintf((mant * 2.0f - 1.0f) * 8.0f);
    int E = e - 1;
    if (q == 8) { q = 0; E += 1; }
    if (E > 8) { E = 8; q = 6; }
    return s | ((unsigned)(E + 7) << 3) | (unsigned)q;
}

__device__ __forceinline__ float2 f8pair(unsigned u) {   // 2 fp8 in low 16 bits
#ifdef HW_FP8
    fv2 r = __builtin_amdgcn_cvt_pk_f32_fp8((int)u, false);
    return make_float2(r.x, r.y);
#else
    return make_float2(sw_dec_e4m3(u & 0xff), sw_dec_e4m3((u >> 8) & 0xff));
#endif
}
__device__ __forceinline__ unsigned f8pack4(float v0, float v1, float v2, float v3) {
#ifdef HW_FP8
    unsigned pk = (unsigned)__builtin_amdgcn_cvt_pk_fp8_f32(v0, v1, 0, false);
    pk = (unsigned)__builtin_amdgcn_cvt_pk_fp8_f32(v2, v3, (int)pk, true);
    return pk;
#else
    return sw_enc_e4m3(v0) | (sw_enc_e4m3(v1) << 8) |
           (sw_enc_e4m3(v2) << 16) | (sw_enc_e4m3(v3) << 24);
#endif
}

// ---------- pass 1: per-WG bucket histogram (LDS), int4 x4 streaming ----------
__global__ __launch_bounds__(PTHR) void k_hist1(const int* __restrict__ col,
                                                int* __restrict__ histG,
                                                int E, int nbkt, int chunk) {
    __shared__ int h[MAXBKT];
    for (int i = threadIdx.x; i < nbkt; i += PTHR) h[i] = 0;
    __syncthreads();
    int s = blockIdx.x * chunk, e = min(E, s + chunk);
    if (s < e) {
        int s4 = s >> 2, e4 = e >> 2;
        const i4* c4 = (const i4*)col;
        int t = s4 + threadIdx.x;
        for (; t + 3 * PTHR < e4; t += 4 * PTHR) {
            i4 a = __builtin_nontemporal_load(c4 + t);
            i4 b = __builtin_nontemporal_load(c4 + t + PTHR);
            i4 c = __builtin_nontemporal_load(c4 + t + 2 * PTHR);
            i4 d = __builtin_nontemporal_load(c4 + t + 3 * PTHR);
            atomicAdd(&h[(unsigned)a.x >> BKT_SH], 1); atomicAdd(&h[(unsigned)a.y >> BKT_SH], 1);
            atomicAdd(&h[(unsigned)a.z >> BKT_SH], 1); atomicAdd(&h[(unsigned)a.w >> BKT_SH], 1);
            atomicAdd(&h[(unsigned)b.x >> BKT_SH], 1); atomicAdd(&h[(unsigned)b.y >> BKT_SH], 1);
            atomicAdd(&h[(unsigned)b.z >> BKT_SH], 1); atomicAdd(&h[(unsigned)b.w >> BKT_SH], 1);
            atomicAdd(&h[(unsigned)c.x >> BKT_SH], 1); atomicAdd(&h[(unsigned)c.y >> BKT_SH], 1);
            atomicAdd(&h[(unsigned)c.z >> BKT_SH], 1); atomicAdd(&h[(unsigned)c.w >> BKT_SH], 1);
            atomicAdd(&h[(unsigned)d.x >> BKT_SH], 1); atomicAdd(&h[(unsigned)d.y >> BKT_SH], 1);
            atomicAdd(&h[(unsigned)d.z >> BKT_SH], 1); atomicAdd(&h[(unsigned)d.w >> BKT_SH], 1);
        }
        for (; t < e4; t += PTHR) {
            i4 a = __builtin_nontemporal_load(c4 + t);
            atomicAdd(&h[(unsigned)a.x >> BKT_SH], 1); atomicAdd(&h[(unsigned)a.y >> BKT_SH], 1);
            atomicAdd(&h[(unsigned)a.z >> BKT_SH], 1); atomicAdd(&h[(unsigned)a.w >> BKT_SH], 1);
        }
        for (int i = (e4 << 2) + threadIdx.x; i < e; i += PTHR)
            atomicAdd(&h[(unsigned)col[i] >> BKT_SH], 1);
    }
    __syncthreads();
    for (int i = threadIdx.x; i < nbkt; i += PTHR)
        histG[(size_t)i * PWG + blockIdx.x] = h[i];
}

// ---------- pass 2a: per-bucket exclusive scan over WGs (in place) ----------
__global__ __launch_bounds__(PWG) void k_hscan_a(int* __restrict__ histG,
                                                 int* __restrict__ total, int nbkt) {
    __shared__ int s[PWG];
    int b = blockIdx.x, t = threadIdx.x;
    int v = histG[(size_t)b * PWG + t];
    s[t] = v;
    __syncthreads();
    for (int d = 1; d < PWG; d <<= 1) {
        int a = (t >= d) ? s[t - d] : 0;
        __syncthreads();
        s[t] += a;
        __syncthreads();
    }
    histG[(size_t)b * PWG + t] = s[t] - v;
    if (t == PWG - 1) total[b] = s[t];
}

// ---------- pass 2b: bucket starts ----------
__global__ __launch_bounds__(1024) void k_hscan_b(const int* __restrict__ total,
                                                  int* __restrict__ bstart, int nbkt) {
    __shared__ int s[1024];
    int t = threadIdx.x;
    int v = (t < nbkt) ? total[t] : 0;
    s[t] = v;
    __syncthreads();
    for (int d = 1; d < 1024; d <<= 1) {
        int a = (t >= d) ? s[t - d] : 0;
        __syncthreads();
        s[t] += a;
        __syncthreads();
    }
    if (t < nbkt) bstart[t] = s[t] - v;
    if (t == nbkt - 1) bstart[nbkt] = s[t];
}

// ---------- pass 3: tile multisplit -> part[] written as coalesced runs ----------
__global__ __launch_bounds__(PPTHR) void k_part(const int* __restrict__ row,
                                                const int* __restrict__ col,
                                                const int* __restrict__ histG,
                                                const int* __restrict__ bstart,
                                                unsigned int* __restrict__ part,
                                                int E, int nbkt, int chunk) {
    __shared__ int hist[MAXBKT], hbase[MAXBKT], curl[MAXBKT], gcur[MAXBKT];
    __shared__ int ssc[PPTHR];
    __shared__ unsigned grouped[TILE];
    __shared__ ushort bkt16[TILE];
    int tid = threadIdx.x, wg = blockIdx.x;
    for (int i = tid; i < nbkt; i += PPTHR)
        gcur[i] = bstart[i] + histG[(size_t)i * PWG + wg];
    int s = wg * chunk, e = min(E, s + chunk);
    for (int ts = s; ts < e; ts += TILE) {
        int te = min(e, ts + TILE), tc = te - ts;
        for (int i = tid; i < nbkt; i += PPTHR) hist[i] = 0;
        __syncthreads();
        for (int i = ts + tid; i < te; i += PPTHR)
            atomicAdd(&hist[(unsigned)col[i] >> BKT_SH], 1);
        __syncthreads();
        // inclusive scan over nbkt (<= PPTHR) with PPTHR threads
        int v = (tid < nbkt) ? hist[tid] : 0;
        ssc[tid] = v;
        __syncthreads();
        for (int d = 1; d < PPTHR; d <<= 1) {
            int a = (tid >= d) ? ssc[tid - d] : 0;
            __syncthreads();
            ssc[tid] += a;
            __syncthreads();
        }
        if (tid < nbkt) { hbase[tid] = ssc[tid] - v; curl[tid] = ssc[tid] - v; }
        __syncthreads();
        // scatter tile into LDS grouped-by-bucket order
        for (int i = ts + tid; i < te; i += PPTHR) {
            int c = col[i], r = row[i];
            int b = (unsigned)c >> BKT_SH;
            int p = atomicAdd(&curl[b], 1);
            grouped[p] = ((unsigned)r << BKT_SH) | (unsigned)(c & (BKT_SZ - 1));
            bkt16[p] = (ushort)b;
        }
        __syncthreads();
        // write out: consecutive q -> consecutive addresses within bucket runs
        for (int q = tid; q < tc; q += PPTHR) {
            int b = bkt16[q];
            part[gcur[b] + (q - hbase[b])] = grouped[q];
        }
        __syncthreads();
        for (int i = tid; i < nbkt; i += PPTHR) gcur[i] += hist[i];
        __syncthreads();
    }
}

// ---------- per-bucket: degrees, offs, dinv; csr built in LDS, copied coalesced ----------
__global__ __launch_bounds__(PTHR) void k_csr(const unsigned int* __restrict__ part,
                                              const int* __restrict__ bstart,
                                              int* __restrict__ offs,
                                              float* __restrict__ dinv,
                                              int* __restrict__ csr,
                                              int N, int E, int nbkt) {
    __shared__ int dg[BKT_SZ], sc[BKT_SZ], cur[BKT_SZ];
    __shared__ int stage[CSR_CAP];
    int b = blockIdx.x, tid = threadIdx.x;   // PTHR == BKT_SZ
    dg[tid] = 0;
    __syncthreads();
    int s = bstart[b], e = bstart[b + 1], cnt = e - s;
    for (int i = s + tid; i < e; i += PTHR)
        atomicAdd(&dg[part[i] & (BKT_SZ - 1)], 1);
    __syncthreads();
    int v = dg[tid];
    sc[tid] = v;
    __syncthreads();
    for (int d = 1; d < BKT_SZ; d <<= 1) {
        int a = (tid >= d) ? sc[tid - d] : 0;
        __syncthreads();
        sc[tid] += a;
        __syncthreads();
    }
    int ex = sc[tid] - v;
    cur[tid] = ex;
    int g = b * BKT_SZ + tid;
    if (g < N) {
        offs[g] = s + ex;
        dinv[g] = rsqrtf((float)v + 1.0f);   // +1 self loop
    }
    if (b == 0 && tid == 0) offs[N] = E;
    __syncthreads();
    if (cnt <= CSR_CAP) {
        for (int i = s + tid; i < e; i += PTHR) {
            unsigned u = part[i];
            int p = atomicAdd(&cur[u & (BKT_SZ - 1)], 1);
            stage[p] = (int)(u >> BKT_SH);
        }
        __syncthreads();
        for (int q = tid; q < cnt; q += PTHR)
            csr[s + q] = stage[q];           // coalesced
    } else {                                  // safety fallback (scattered)
        for (int i = s + tid; i < e; i += PTHR) {
            unsigned u = part[i];
            int p = atomicAdd(&cur[u & (BKT_SZ - 1)], 1);
            csr[s + p] = (int)(u >> BKT_SH);
        }
    }
}

// ---------- xws = dinv * (x @ W1), fp8 e4m3 (64B rows) ----------
__global__ __launch_bounds__(256) void k_gemm1(const float* __restrict__ x,
                                               const float* __restrict__ W1,
                                               const float* __restrict__ dinv,
                                               unsigned int* __restrict__ xw8,
                                               int N) {
    __shared__ float xs[64 * 132];
    __shared__ float ws[128 * 64];
    int tid = threadIdx.x;
    int row0 = blockIdx.x * 64;

    const float4* w4 = (const float4*)W1;
    float4* ws4 = (float4*)ws;
#pragma unroll
    for (int i = 0; i < 8; i++) ws4[tid + 256 * i] = w4[tid + 256 * i];

#pragma unroll
    for (int i = 0; i < 8; i++) {
        int idx = tid + 256 * i;
        int r = idx >> 5;
        int c = idx & 31;
        f4 v = {0.f, 0.f, 0.f, 0.f};
        int gr = row0 + r;
        if (gr < N) v = __builtin_nontemporal_load((const f4*)x + (size_t)gr * 32 + c);
        *(f4*)&xs[r * 132 + c * 4] = v;
    }
    __syncthreads();

    int tx = tid & 15, ty = tid >> 4;
    float acc[4][4] = {};
#pragma unroll 4
    for (int k = 0; k < 128; k++) {
        float4 wv = *(const float4*)&ws[k * 64 + tx * 4];
#pragma unroll
        for (int i = 0; i < 4; i++) {
            float xv = xs[(ty * 4 + i) * 132 + k];
            acc[i][0] += xv * wv.x;
            acc[i][1] += xv * wv.y;
            acc[i][2] += xv * wv.z;
            acc[i][3] += xv * wv.w;
        }
    }
#pragma unroll
    for (int i = 0; i < 4; i++) {
        int gr = row0 + ty * 4 + i;
        if (gr < N) {
            float dsc = dinv[gr];
            unsigned pk = f8pack4(acc[i][0] * dsc, acc[i][1] * dsc,
                                  acc[i][2] * dsc, acc[i][3] * dsc);
            xw8[(size_t)gr * 16 + tx] = pk;   // row = 16 u32 = 64 fp8
        }
    }
}

// ---------- aggregation: one wave per node, half-wave ushort fp8 gathers ----------
__global__ __launch_bounds__(256) void k_agg(const ushort* __restrict__ xw8,
                                             const int* __restrict__ csr,
                                             const int* __restrict__ offs,
                                             const float* __restrict__ dinv,
                                             const float* __restrict__ b1,
                                             const float* __restrict__ W2,
                                             float* __restrict__ yp, int N) {
    int wid = (blockIdx.x * blockDim.x + threadIdx.x) >> 6;
    int lane = threadIdx.x & 63;
    if (wid >= N) return;
    int m = lane & 31, half = lane >> 5;

    float di = dinv[wid];
    float2 bv = ((const float2*)b1)[m];
    float2 wv = ((const float2*)W2)[m];

    float a0 = 0.f, a1 = 0.f;
    if (half == 0) {          // self loop counted once
        float2 sv = f8pair(xw8[(size_t)wid * 32 + m]);
        a0 += sv.x; a1 += sv.y;
    }
    int p = offs[wid], pe = offs[wid + 1];
    for (; p + 16 <= pe; p += 16) {
        int j0 = csr[p + 0 + half];
        int j1 = csr[p + 2 + half];
        int j2 = csr[p + 4 + half];
        int j3 = csr[p + 6 + half];
        int j4 = csr[p + 8 + half];
        int j5 = csr[p + 10 + half];
        int j6 = csr[p + 12 + half];
        int j7 = csr[p + 14 + half];
        ushort u0 = xw8[(size_t)j0 * 32 + m];
        ushort u1 = xw8[(size_t)j1 * 32 + m];
        ushort u2 = xw8[(size_t)j2 * 32 + m];
        ushort u3 = xw8[(size_t)j3 * 32 + m];
        ushort u4 = xw8[(size_t)j4 * 32 + m];
        ushort u5 = xw8[(size_t)j5 * 32 + m];
        ushort u6 = xw8[(size_t)j6 * 32 + m];
        ushort u7 = xw8[(size_t)j7 * 32 + m];
        float2 v0 = f8pair(u0), v1 = f8pair(u1), v2 = f8pair(u2), v3 = f8pair(u3);
        float2 v4 = f8pair(u4), v5 = f8pair(u5), v6 = f8pair(u6), v7 = f8pair(u7);
        a0 += ((v0.x + v1.x) + (v2.x + v3.x)) + ((v4.x + v5.x) + (v6.x + v7.x));
        a1 += ((v0.y + v1.y) + (v2.y + v3.y)) + ((v4.y + v5.y) + (v6.y + v7.y));
    }
    for (; p + 8 <= pe; p += 8) {
        int j0 = csr[p + 0 + half];
        int j1 = csr[p + 2 + half];
        int j2 = csr[p + 4 + half];
        int j3 = csr[p + 6 + half];
        float2 v0 = f8pair(xw8[(size_t)j0 * 32 + m]);
        float2 v1 = f8pair(xw8[(size_t)j1 * 32 + m]);
        float2 v2 = f8pair(xw8[(size_t)j2 * 32 + m]);
        float2 v3 = f8pair(xw8[(size_t)j3 * 32 + m]);
        a0 += (v0.x + v1.x) + (v2.x + v3.x);
        a1 += (v0.y + v1.y) + (v2.y + v3.y);
    }
    for (; p + 2 <= pe; p += 2) {
        int j = csr[p + half];
        float2 v = f8pair(xw8[(size_t)j * 32 + m]);
        a0 += v.x; a1 += v.y;
    }
    if (p < pe && half == 0) {     // odd tail edge
        int j = csr[p];
        float2 v = f8pair(xw8[(size_t)j * 32 + m]);
        a0 += v.x; a1 += v.y;
    }
    a0 += __shfl_xor(a0, 32, 64);
    a1 += __shfl_xor(a1, 32, 64);
    float h0 = fmaxf(bv.x + di * a0, 0.f);
    float h1 = fmaxf(bv.y + di * a1, 0.f);
    float v = h0 * wv.x + h1 * wv.y;
#pragma unroll
    for (int d = 16; d > 0; d >>= 1) v += __shfl_xor(v, d, 64);
    if (lane == 0) yp[wid] = di * v;
}

// ---------- final: wave-per-node over CSR, per-block partials ----------
__global__ __launch_bounds__(256) void k_final2(const int* __restrict__ csr,
                                                const int* __restrict__ offs,
                                                const float* __restrict__ dinv,
                                                const float* __restrict__ yp,
                                                float* __restrict__ partial, int N) {
    int lane = threadIdx.x & 63, w = threadIdx.x >> 6;
    int nwave_tot = gridDim.x * 4;
    int wid0 = blockIdx.x * 4 + w;
    float wpart = 0.f;
    for (int i = wid0; i < N; i += nwave_tot) {
        int p0 = offs[i], p1 = offs[i + 1];
        float s = (lane == 0) ? yp[i] : 0.f;
        for (int p = p0 + lane; p < p1; p += 64)
            s += yp[csr[p]];
#pragma unroll
        for (int d = 32; d > 0; d >>= 1) s += __shfl_xor(s, d, 64);
        if (lane == 0) wpart += dinv[i] * s;
    }
    __shared__ float wsum[4];
    if (lane == 0) wsum[w] = wpart;
    __syncthreads();
    if (threadIdx.x == 0)
        partial[blockIdx.x] = (wsum[0] + wsum[1]) + (wsum[2] + wsum[3]);
}

// ---------- reduce partials + write ----------
__global__ __launch_bounds__(256) void k_write(const float* __restrict__ partial,
                                               const float* __restrict__ b2,
                                               float* __restrict__ out, int nb, int N) {
    float s = 0.f;
    for (int i = threadIdx.x; i < nb; i += 256) s += partial[i];
#pragma unroll
    for (int d = 32; d > 0; d >>= 1) s += __shfl_xor(s, d, 64);
    __shared__ float wsum[4];
    int lane = threadIdx.x & 63, w = threadIdx.x >> 6;
    if (lane == 0) wsum[w] = s;
    __syncthreads();
    if (threadIdx.x == 0)
        out[0] = b2[0] + ((wsum[0] + wsum[1]) + (wsum[2] + wsum[3])) / (float)N;
}

extern "C" void kernel_launch(void* const* d_in, const int* in_sizes, int n_in,
                              void* d_out, int out_size, void* d_ws, size_t ws_size,
                              hipStream_t stream) {
    const float* x  = (const float*)d_in[0];
    const int*   ei = (const int*)d_in[1];
    const float* W1 = (const float*)d_in[2];
    const float* b1 = (const float*)d_in[3];
    const float* W2 = (const float*)d_in[4];
    const float* b2 = (const float*)d_in[5];

    int N = in_sizes[0] / F_IN;
    int E = in_sizes[1] / 2;
    const int* erow = ei;        // sources
    const int* ecol = ei + E;    // targets

    int NBKT = (N + BKT_SZ - 1) >> BKT_SH;          // 391
    int chunk = (((E + PWG - 1) / PWG) + 3) & ~3;   // 4-aligned chunks

    char* w = (char*)d_ws;
    auto take = [&](size_t bytes) {
        char* p = w;
        w += (bytes + 255) & ~(size_t)255;
        return p;
    };
    int*          histG   = (int*)take((size_t)NBKT * PWG * 4);
    int*          total   = (int*)take((size_t)NBKT * 4);
    int*          bstart  = (int*)take((size_t)(NBKT + 1) * 4);
    unsigned int* part    = (unsigned int*)take((size_t)E * 4);
    int*          csr     = (int*)take((size_t)E * 4);
    int*          offs    = (int*)take((size_t)(N + 1) * 4);
    float*        dinv    = (float*)take((size_t)N * 4);
    float*        yp      = (float*)take((size_t)N * 4);
    float*        partial = (float*)take((size_t)FINBLK * 4);
    unsigned int* xw8     = (unsigned int*)take((size_t)N * H_DIM);
    (void)ws_size;

    float* out = (float*)d_out;

    k_hist1<<<PWG, PTHR, 0, stream>>>(ecol, histG, E, NBKT, chunk);
    k_hscan_a<<<NBKT, PWG, 0, stream>>>(histG, total, NBKT);
    k_hscan_b<<<1, 1024, 0, stream>>>(total, bstart, NBKT);
    k_part<<<PWG, PPTHR, 0, stream>>>(erow, ecol, histG, bstart, part, E, NBKT, chunk);
    k_csr<<<NBKT, PTHR, 0, stream>>>(part, bstart, offs, dinv, csr, N, E, NBKT);
    k_gemm1<<<(N + 63) / 64, 256, 0, stream>>>(x, W1, dinv, xw8, N);
    k_agg<<<((size_t)N * 64 + 255) / 256, 256, 0, stream>>>((const ushort*)xw8, csr, offs, dinv, b1, W2, yp, N);
    k_final2<<<FINBLK, 256, 0, stream>>>(csr, offs, dinv, yp, partial, N);
    k_write<<<1, 256, 0, stream>>>(partial, b2, out, FINBLK, N);
}